// Round 8
// baseline (191.160 us; speedup 1.0000x reference)
//
#include <hip/hip_runtime.h>

#define IN_DIM 98304
#define H1 256
#define H2 32
#define NZ_MAX 512
#define TS 64

typedef float f32x4 __attribute__((ext_vector_type(4)));
typedef unsigned short u16;
typedef u16 u16x8 __attribute__((ext_vector_type(8)));

__device__ __forceinline__ u16 f2bf(float f) {          // round-to-nearest-even
    unsigned u = __builtin_bit_cast(unsigned, f);
    u = (u + 0x7FFFu + ((u >> 16) & 1u)) >> 16;
    return (u16)u;
}
__device__ __forceinline__ float bf2f(u16 h) {
    return __builtin_bit_cast(float, (unsigned)h << 16);
}

// ---- Transpose W1 [H1][IN_DIM] f32 -> W1T [IN_DIM][H1] bf16 (64x64 tiles via LDS).
//      Unchanged from R6. ----
__global__ __launch_bounds__(256) void transpose_w1_bf16(const float* __restrict__ W1,
                                                         u16* __restrict__ W1T) {
    __shared__ float tile[TS][TS + 4];     // [col][row]
    const int cb = blockIdx.x * TS;        // W1 column base
    const int rb = blockIdx.y * TS;        // W1 row base
    const int tx = threadIdx.x & 15;
    const int ty = threadIdx.x >> 4;       // 0..15

    #pragma unroll
    for (int rr = 0; rr < 4; ++rr) {
        const int r = rr * 16 + ty;        // 0..63
        f32x4 v = __builtin_nontemporal_load(reinterpret_cast<const f32x4*>(
            &W1[(size_t)(rb + r) * IN_DIM + cb + tx * 4]));
        tile[tx * 4 + 0][r] = v.x;
        tile[tx * 4 + 1][r] = v.y;
        tile[tx * 4 + 2][r] = v.z;
        tile[tx * 4 + 3][r] = v.w;
    }
    __syncthreads();
    // write-out: 64 rows x 64 cols = 512 u16x8 chunks, 2 per thread
    #pragma unroll
    for (int it = 0; it < 2; ++it) {
        const int P = it * 256 + threadIdx.x;
        const int r = P >> 3;              // W1T row within tile (= W1 col) 0..63
        const int q = (P & 7) * 8;         // W1T col within tile (= W1 row) 0..56
        u16x8 w;
        #pragma unroll
        for (int j = 0; j < 8; ++j)
            w[j] = f2bf(tile[r][q + j]);
        *reinterpret_cast<u16x8*>(&W1T[(size_t)(cb + r) * H1 + rb + q]) = w;
    }
}

// ---- Fused NNUE forward: scan (PLAIN cached loads — the A/B variable) ->
//      gather(bf16) -> fc2 -> head. Otherwise byte-identical to R6. ----
__global__ __launch_bounds__(256) void nnue_fwd_t(
    const float* __restrict__ x,
    const u16*   __restrict__ W1T,     // transposed bf16 [IN_DIM][H1]
    const float* __restrict__ b1,
    const float* __restrict__ W2,
    const float* __restrict__ b2,
    const float* __restrict__ Wout,
    const float* __restrict__ bout,
    float* __restrict__ out)
{
    __shared__ int   s_idx[NZ_MAX];
    __shared__ float s_val[NZ_MAX];
    __shared__ float s_h1[H1];
    __shared__ float s_h2[H2];
    __shared__ int   s_cnt;

    const int tid = threadIdx.x;
    const int row = blockIdx.x;

    if (tid == 0) s_cnt = 0;
    __syncthreads();

    // ---- Phase 1: scan x row. 8 plain f32x4 loads in flight, then test. ----
    const f32x4* xr = reinterpret_cast<const f32x4*>(x + (size_t)row * IN_DIM);
    for (int o = 0; o < IN_DIM / (256 * 4 * 8); ++o) {   // 12 outer iters
        f32x4 v[8];
        #pragma unroll
        for (int u = 0; u < 8; ++u)
            v[u] = xr[o * 2048 + u * 256 + tid];         // A/B: NT hint removed
        #pragma unroll
        for (int u = 0; u < 8; ++u) {
            if (v[u].x != 0.f || v[u].y != 0.f || v[u].z != 0.f || v[u].w != 0.f) {
                const int col = (o * 2048 + u * 256 + tid) * 4;
                if (v[u].x != 0.f) { int p = atomicAdd(&s_cnt, 1); if (p < NZ_MAX) { s_idx[p] = col;     s_val[p] = v[u].x; } }
                if (v[u].y != 0.f) { int p = atomicAdd(&s_cnt, 1); if (p < NZ_MAX) { s_idx[p] = col + 1; s_val[p] = v[u].y; } }
                if (v[u].z != 0.f) { int p = atomicAdd(&s_cnt, 1); if (p < NZ_MAX) { s_idx[p] = col + 2; s_val[p] = v[u].z; } }
                if (v[u].w != 0.f) { int p = atomicAdd(&s_cnt, 1); if (p < NZ_MAX) { s_idx[p] = col + 3; s_val[p] = v[u].w; } }
            }
        }
    }
    __syncthreads();

    int cnt = s_cnt;
    if (cnt > NZ_MAX) cnt = NZ_MAX;
    const int cntp = (cnt + 7) & ~7;       // pad to multiple of 8 (cntp <= 512)
    if (tid < cntp - cnt) { s_idx[cnt + tid] = 0; s_val[cnt + tid] = 0.f; }
    __syncthreads();

    // ---- Phase 2: h1[t] = relu(b1[t] + sum_k val[k] * W1T[idx[k]][t]), 8-wide ILP ----
    {
        float acc = b1[tid];
        for (int k = 0; k < cntp; k += 8) {
            const int   i0 = s_idx[k + 0], i1 = s_idx[k + 1], i2 = s_idx[k + 2], i3 = s_idx[k + 3];
            const int   i4 = s_idx[k + 4], i5 = s_idx[k + 5], i6 = s_idx[k + 6], i7 = s_idx[k + 7];
            const float c0 = s_val[k + 0], c1 = s_val[k + 1], c2 = s_val[k + 2], c3 = s_val[k + 3];
            const float c4 = s_val[k + 4], c5 = s_val[k + 5], c6 = s_val[k + 6], c7 = s_val[k + 7];
            const float a0 = bf2f(W1T[(size_t)i0 * H1 + tid]);   // 128B/wave contiguous
            const float a1 = bf2f(W1T[(size_t)i1 * H1 + tid]);
            const float a2 = bf2f(W1T[(size_t)i2 * H1 + tid]);
            const float a3 = bf2f(W1T[(size_t)i3 * H1 + tid]);
            const float a4 = bf2f(W1T[(size_t)i4 * H1 + tid]);
            const float a5 = bf2f(W1T[(size_t)i5 * H1 + tid]);
            const float a6 = bf2f(W1T[(size_t)i6 * H1 + tid]);
            const float a7 = bf2f(W1T[(size_t)i7 * H1 + tid]);
            acc += ((c0 * a0 + c1 * a1) + (c2 * a2 + c3 * a3))
                 + ((c4 * a4 + c5 * a5) + (c6 * a6 + c7 * a7));
        }
        s_h1[tid] = fmaxf(acc, 0.f);
    }
    __syncthreads();

    // ---- Phase 3: h2[j] = relu(b2[j] + W2[j,:] . h1)  (8 lanes per neuron) ----
    {
        const int j = tid >> 3;
        const int p = tid & 7;
        float part = 0.f;
        const float* w2r = W2 + j * H1 + p;
        #pragma unroll
        for (int k = 0; k < H1 / 8; ++k)
            part += w2r[8 * k] * s_h1[p + 8 * k];
        part += __shfl_xor(part, 1);
        part += __shfl_xor(part, 2);
        part += __shfl_xor(part, 4);
        if (p == 0) s_h2[j] = fmaxf(part + b2[j], 0.f);
    }
    __syncthreads();

    // ---- Phase 4: out[row] = bout + Wout . h2 ----
    if (tid < 32) {
        float t = Wout[tid] * s_h2[tid];
        t += __shfl_xor(t, 1);
        t += __shfl_xor(t, 2);
        t += __shfl_xor(t, 4);
        t += __shfl_xor(t, 8);
        t += __shfl_xor(t, 16);
        if (tid == 0) out[row] = t + bout[0];
    }
}

// ---- Fallback (ws too small): fused scan + row-major f32 gather ----
__global__ __launch_bounds__(256) void nnue_direct(
    const float* __restrict__ x, const float* __restrict__ W1,
    const float* __restrict__ b1, const float* __restrict__ W2,
    const float* __restrict__ b2, const float* __restrict__ Wout,
    const float* __restrict__ bout, float* __restrict__ out)
{
    __shared__ int   s_idx[NZ_MAX];
    __shared__ float s_val[NZ_MAX];
    __shared__ float s_h1[H1];
    __shared__ float s_h2[H2];
    __shared__ int   s_cnt;
    const int tid = threadIdx.x;
    const int row = blockIdx.x;
    if (tid == 0) s_cnt = 0;
    __syncthreads();
    const f32x4* xr = reinterpret_cast<const f32x4*>(x + (size_t)row * IN_DIM);
    for (int o = 0; o < IN_DIM / (256 * 4 * 8); ++o) {
        f32x4 v[8];
        #pragma unroll
        for (int u = 0; u < 8; ++u)
            v[u] = xr[o * 2048 + u * 256 + tid];
        #pragma unroll
        for (int u = 0; u < 8; ++u) {
            if (v[u].x != 0.f || v[u].y != 0.f || v[u].z != 0.f || v[u].w != 0.f) {
                const int col = (o * 2048 + u * 256 + tid) * 4;
                if (v[u].x != 0.f) { int p = atomicAdd(&s_cnt, 1); if (p < NZ_MAX) { s_idx[p] = col;     s_val[p] = v[u].x; } }
                if (v[u].y != 0.f) { int p = atomicAdd(&s_cnt, 1); if (p < NZ_MAX) { s_idx[p] = col + 1; s_val[p] = v[u].y; } }
                if (v[u].z != 0.f) { int p = atomicAdd(&s_cnt, 1); if (p < NZ_MAX) { s_idx[p] = col + 2; s_val[p] = v[u].z; } }
                if (v[u].w != 0.f) { int p = atomicAdd(&s_cnt, 1); if (p < NZ_MAX) { s_idx[p] = col + 3; s_val[p] = v[u].w; } }
            }
        }
    }
    __syncthreads();
    int cnt = s_cnt; if (cnt > NZ_MAX) cnt = NZ_MAX;
    const int cntp = (cnt + 3) & ~3;
    if (tid < cntp - cnt) { s_idx[cnt + tid] = 0; s_val[cnt + tid] = 0.f; }
    __syncthreads();
    float acc = b1[tid];
    const float* w1r = W1 + (size_t)tid * IN_DIM;
    for (int k = 0; k < cntp; k += 4) {
        const float a0 = s_val[k + 0] * w1r[s_idx[k + 0]];
        const float a1 = s_val[k + 1] * w1r[s_idx[k + 1]];
        const float a2 = s_val[k + 2] * w1r[s_idx[k + 2]];
        const float a3 = s_val[k + 3] * w1r[s_idx[k + 3]];
        acc += (a0 + a1) + (a2 + a3);
    }
    s_h1[tid] = fmaxf(acc, 0.f);
    __syncthreads();
    {
        const int j = tid >> 3;
        const int p = tid & 7;
        float part = 0.f;
        const float* w2r = W2 + j * H1 + p;
        #pragma unroll
        for (int k = 0; k < H1 / 8; ++k)
            part += w2r[8 * k] * s_h1[p + 8 * k];
        part += __shfl_xor(part, 1);
        part += __shfl_xor(part, 2);
        part += __shfl_xor(part, 4);
        if (p == 0) s_h2[j] = fmaxf(part + b2[j], 0.f);
    }
    __syncthreads();
    if (tid < 32) {
        float t = Wout[tid] * s_h2[tid];
        t += __shfl_xor(t, 1);
        t += __shfl_xor(t, 2);
        t += __shfl_xor(t, 4);
        t += __shfl_xor(t, 8);
        t += __shfl_xor(t, 16);
        if (tid == 0) out[row] = t + bout[0];
    }
}

extern "C" void kernel_launch(void* const* d_in, const int* in_sizes, int n_in,
                              void* d_out, int out_size, void* d_ws, size_t ws_size,
                              hipStream_t stream) {
    const float* x    = (const float*)d_in[0];
    const float* W1   = (const float*)d_in[1];
    const float* b1   = (const float*)d_in[2];
    const float* W2   = (const float*)d_in[3];
    const float* b2   = (const float*)d_in[4];
    const float* Wout = (const float*)d_in[5];
    const float* bout = (const float*)d_in[6];
    float* out = (float*)d_out;

    const int B = out_size;                                        // 2048 rows
    const size_t w1t_bytes = (size_t)IN_DIM * H1 * sizeof(u16);    // 50.3 MB

    if (ws_size >= w1t_bytes) {
        u16* W1T = (u16*)d_ws;
        transpose_w1_bf16<<<dim3(IN_DIM / TS, H1 / TS), 256, 0, stream>>>(W1, W1T);
        nnue_fwd_t<<<B, 256, 0, stream>>>(x, W1T, b1, W2, b2, Wout, bout, out);
    } else {
        nnue_direct<<<B, 256, 0, stream>>>(x, W1, b1, W2, b2, Wout, bout, out);
    }
}

// Round 9
// 169.180 us; speedup vs baseline: 1.1299x; 1.1299x over previous
//
#include <hip/hip_runtime.h>

#define IN_DIM 98304
#define H1 256
#define H2 32
#define NZ_MAX 512
#define TS 64

typedef float f32x4 __attribute__((ext_vector_type(4)));
typedef unsigned short u16;
typedef u16 u16x8 __attribute__((ext_vector_type(8)));

__device__ __forceinline__ u16 f2bf(float f) {          // round-to-nearest-even
    unsigned u = __builtin_bit_cast(unsigned, f);
    u = (u + 0x7FFFu + ((u >> 16) & 1u)) >> 16;
    return (u16)u;
}
__device__ __forceinline__ float bf2f(u16 h) {
    return __builtin_bit_cast(float, (unsigned)h << 16);
}

// ---- Transpose W1 [H1][IN_DIM] f32 -> W1T [IN_DIM][H1] bf16 (64x64 tiles via LDS) ----
__global__ __launch_bounds__(256) void transpose_w1_bf16(const float* __restrict__ W1,
                                                         u16* __restrict__ W1T) {
    __shared__ float tile[TS][TS + 4];     // [col][row]
    const int cb = blockIdx.x * TS;        // W1 column base
    const int rb = blockIdx.y * TS;        // W1 row base
    const int tx = threadIdx.x & 15;
    const int ty = threadIdx.x >> 4;       // 0..15

    #pragma unroll
    for (int rr = 0; rr < 4; ++rr) {
        const int r = rr * 16 + ty;        // 0..63
        f32x4 v = __builtin_nontemporal_load(reinterpret_cast<const f32x4*>(
            &W1[(size_t)(rb + r) * IN_DIM + cb + tx * 4]));
        tile[tx * 4 + 0][r] = v.x;
        tile[tx * 4 + 1][r] = v.y;
        tile[tx * 4 + 2][r] = v.z;
        tile[tx * 4 + 3][r] = v.w;
    }
    __syncthreads();
    // write-out: 64 rows x 64 cols = 512 u16x8 chunks, 2 per thread
    #pragma unroll
    for (int it = 0; it < 2; ++it) {
        const int P = it * 256 + threadIdx.x;
        const int r = P >> 3;              // W1T row within tile (= W1 col) 0..63
        const int q = (P & 7) * 8;         // W1T col within tile (= W1 row) 0..56
        u16x8 w;
        #pragma unroll
        for (int j = 0; j < 8; ++j)
            w[j] = f2bf(tile[r][q + j]);
        *reinterpret_cast<u16x8*>(&W1T[(size_t)(cb + r) * H1 + rb + q]) = w;
    }
}

// ---- Fused NNUE forward: NT scan -> gather(bf16, coalesced) -> fc2 -> head ----
__global__ __launch_bounds__(256) void nnue_fwd_t(
    const float* __restrict__ x,
    const u16*   __restrict__ W1T,     // transposed bf16 [IN_DIM][H1]
    const float* __restrict__ b1,
    const float* __restrict__ W2,
    const float* __restrict__ b2,
    const float* __restrict__ Wout,
    const float* __restrict__ bout,
    float* __restrict__ out)
{
    __shared__ int   s_idx[NZ_MAX];
    __shared__ float s_val[NZ_MAX];
    __shared__ float s_h1[H1];
    __shared__ float s_h2[H2];
    __shared__ int   s_cnt;

    const int tid = threadIdx.x;
    const int row = blockIdx.x;

    if (tid == 0) s_cnt = 0;
    __syncthreads();

    // ---- Phase 1: scan x row. 8 nontemporal f32x4 loads in flight, then test.
    //      NT hint is load-bearing: without it the x stream evicts W1T from
    //      L2/L3 and the kernel regresses 170->191 us (R7 A/B). ----
    const f32x4* xr = reinterpret_cast<const f32x4*>(x + (size_t)row * IN_DIM);
    for (int o = 0; o < IN_DIM / (256 * 4 * 8); ++o) {   // 12 outer iters
        f32x4 v[8];
        #pragma unroll
        for (int u = 0; u < 8; ++u)
            v[u] = __builtin_nontemporal_load(&xr[o * 2048 + u * 256 + tid]);
        #pragma unroll
        for (int u = 0; u < 8; ++u) {
            if (v[u].x != 0.f || v[u].y != 0.f || v[u].z != 0.f || v[u].w != 0.f) {
                const int col = (o * 2048 + u * 256 + tid) * 4;
                if (v[u].x != 0.f) { int p = atomicAdd(&s_cnt, 1); if (p < NZ_MAX) { s_idx[p] = col;     s_val[p] = v[u].x; } }
                if (v[u].y != 0.f) { int p = atomicAdd(&s_cnt, 1); if (p < NZ_MAX) { s_idx[p] = col + 1; s_val[p] = v[u].y; } }
                if (v[u].z != 0.f) { int p = atomicAdd(&s_cnt, 1); if (p < NZ_MAX) { s_idx[p] = col + 2; s_val[p] = v[u].z; } }
                if (v[u].w != 0.f) { int p = atomicAdd(&s_cnt, 1); if (p < NZ_MAX) { s_idx[p] = col + 3; s_val[p] = v[u].w; } }
            }
        }
    }
    __syncthreads();

    int cnt = s_cnt;
    if (cnt > NZ_MAX) cnt = NZ_MAX;
    const int cntp = (cnt + 7) & ~7;       // pad to multiple of 8 (cntp <= 512)
    if (tid < cntp - cnt) { s_idx[cnt + tid] = 0; s_val[cnt + tid] = 0.f; }
    __syncthreads();

    // ---- Phase 2: h1[t] = relu(b1[t] + sum_k val[k] * W1T[idx[k]][t]), 8-wide ILP ----
    {
        float acc = b1[tid];
        for (int k = 0; k < cntp; k += 8) {
            const int   i0 = s_idx[k + 0], i1 = s_idx[k + 1], i2 = s_idx[k + 2], i3 = s_idx[k + 3];
            const int   i4 = s_idx[k + 4], i5 = s_idx[k + 5], i6 = s_idx[k + 6], i7 = s_idx[k + 7];
            const float c0 = s_val[k + 0], c1 = s_val[k + 1], c2 = s_val[k + 2], c3 = s_val[k + 3];
            const float c4 = s_val[k + 4], c5 = s_val[k + 5], c6 = s_val[k + 6], c7 = s_val[k + 7];
            const float a0 = bf2f(W1T[(size_t)i0 * H1 + tid]);   // 128B/wave contiguous
            const float a1 = bf2f(W1T[(size_t)i1 * H1 + tid]);
            const float a2 = bf2f(W1T[(size_t)i2 * H1 + tid]);
            const float a3 = bf2f(W1T[(size_t)i3 * H1 + tid]);
            const float a4 = bf2f(W1T[(size_t)i4 * H1 + tid]);
            const float a5 = bf2f(W1T[(size_t)i5 * H1 + tid]);
            const float a6 = bf2f(W1T[(size_t)i6 * H1 + tid]);
            const float a7 = bf2f(W1T[(size_t)i7 * H1 + tid]);
            acc += ((c0 * a0 + c1 * a1) + (c2 * a2 + c3 * a3))
                 + ((c4 * a4 + c5 * a5) + (c6 * a6 + c7 * a7));
        }
        s_h1[tid] = fmaxf(acc, 0.f);
    }
    __syncthreads();

    // ---- Phase 3: h2[j] = relu(b2[j] + W2[j,:] . h1)  (8 lanes per neuron) ----
    {
        const int j = tid >> 3;
        const int p = tid & 7;
        float part = 0.f;
        const float* w2r = W2 + j * H1 + p;
        #pragma unroll
        for (int k = 0; k < H1 / 8; ++k)
            part += w2r[8 * k] * s_h1[p + 8 * k];
        part += __shfl_xor(part, 1);
        part += __shfl_xor(part, 2);
        part += __shfl_xor(part, 4);
        if (p == 0) s_h2[j] = fmaxf(part + b2[j], 0.f);
    }
    __syncthreads();

    // ---- Phase 4: out[row] = bout + Wout . h2 ----
    if (tid < 32) {
        float t = Wout[tid] * s_h2[tid];
        t += __shfl_xor(t, 1);
        t += __shfl_xor(t, 2);
        t += __shfl_xor(t, 4);
        t += __shfl_xor(t, 8);
        t += __shfl_xor(t, 16);
        if (tid == 0) out[row] = t + bout[0];
    }
}

// ---- Fallback (ws too small): fused scan + row-major f32 gather ----
__global__ __launch_bounds__(256) void nnue_direct(
    const float* __restrict__ x, const float* __restrict__ W1,
    const float* __restrict__ b1, const float* __restrict__ W2,
    const float* __restrict__ b2, const float* __restrict__ Wout,
    const float* __restrict__ bout, float* __restrict__ out)
{
    __shared__ int   s_idx[NZ_MAX];
    __shared__ float s_val[NZ_MAX];
    __shared__ float s_h1[H1];
    __shared__ float s_h2[H2];
    __shared__ int   s_cnt;
    const int tid = threadIdx.x;
    const int row = blockIdx.x;
    if (tid == 0) s_cnt = 0;
    __syncthreads();
    const f32x4* xr = reinterpret_cast<const f32x4*>(x + (size_t)row * IN_DIM);
    for (int o = 0; o < IN_DIM / (256 * 4 * 8); ++o) {
        f32x4 v[8];
        #pragma unroll
        for (int u = 0; u < 8; ++u)
            v[u] = __builtin_nontemporal_load(&xr[o * 2048 + u * 256 + tid]);
        #pragma unroll
        for (int u = 0; u < 8; ++u) {
            if (v[u].x != 0.f || v[u].y != 0.f || v[u].z != 0.f || v[u].w != 0.f) {
                const int col = (o * 2048 + u * 256 + tid) * 4;
                if (v[u].x != 0.f) { int p = atomicAdd(&s_cnt, 1); if (p < NZ_MAX) { s_idx[p] = col;     s_val[p] = v[u].x; } }
                if (v[u].y != 0.f) { int p = atomicAdd(&s_cnt, 1); if (p < NZ_MAX) { s_idx[p] = col + 1; s_val[p] = v[u].y; } }
                if (v[u].z != 0.f) { int p = atomicAdd(&s_cnt, 1); if (p < NZ_MAX) { s_idx[p] = col + 2; s_val[p] = v[u].z; } }
                if (v[u].w != 0.f) { int p = atomicAdd(&s_cnt, 1); if (p < NZ_MAX) { s_idx[p] = col + 3; s_val[p] = v[u].w; } }
            }
        }
    }
    __syncthreads();
    int cnt = s_cnt; if (cnt > NZ_MAX) cnt = NZ_MAX;
    const int cntp = (cnt + 3) & ~3;
    if (tid < cntp - cnt) { s_idx[cnt + tid] = 0; s_val[cnt + tid] = 0.f; }
    __syncthreads();
    float acc = b1[tid];
    const float* w1r = W1 + (size_t)tid * IN_DIM;
    for (int k = 0; k < cntp; k += 4) {
        const float a0 = s_val[k + 0] * w1r[s_idx[k + 0]];
        const float a1 = s_val[k + 1] * w1r[s_idx[k + 1]];
        const float a2 = s_val[k + 2] * w1r[s_idx[k + 2]];
        const float a3 = s_val[k + 3] * w1r[s_idx[k + 3]];
        acc += (a0 + a1) + (a2 + a3);
    }
    s_h1[tid] = fmaxf(acc, 0.f);
    __syncthreads();
    {
        const int j = tid >> 3;
        const int p = tid & 7;
        float part = 0.f;
        const float* w2r = W2 + j * H1 + p;
        #pragma unroll
        for (int k = 0; k < H1 / 8; ++k)
            part += w2r[8 * k] * s_h1[p + 8 * k];
        part += __shfl_xor(part, 1);
        part += __shfl_xor(part, 2);
        part += __shfl_xor(part, 4);
        if (p == 0) s_h2[j] = fmaxf(part + b2[j], 0.f);
    }
    __syncthreads();
    if (tid < 32) {
        float t = Wout[tid] * s_h2[tid];
        t += __shfl_xor(t, 1);
        t += __shfl_xor(t, 2);
        t += __shfl_xor(t, 4);
        t += __shfl_xor(t, 8);
        t += __shfl_xor(t, 16);
        if (tid == 0) out[row] = t + bout[0];
    }
}

extern "C" void kernel_launch(void* const* d_in, const int* in_sizes, int n_in,
                              void* d_out, int out_size, void* d_ws, size_t ws_size,
                              hipStream_t stream) {
    const float* x    = (const float*)d_in[0];
    const float* W1   = (const float*)d_in[1];
    const float* b1   = (const float*)d_in[2];
    const float* W2   = (const float*)d_in[3];
    const float* b2   = (const float*)d_in[4];
    const float* Wout = (const float*)d_in[5];
    const float* bout = (const float*)d_in[6];
    float* out = (float*)d_out;

    const int B = out_size;                                        // 2048 rows
    const size_t w1t_bytes = (size_t)IN_DIM * H1 * sizeof(u16);    // 50.3 MB

    if (ws_size >= w1t_bytes) {
        u16* W1T = (u16*)d_ws;
        transpose_w1_bf16<<<dim3(IN_DIM / TS, H1 / TS), 256, 0, stream>>>(W1, W1T);
        nnue_fwd_t<<<B, 256, 0, stream>>>(x, W1T, b1, W2, b2, Wout, bout, out);
    } else {
        nnue_direct<<<B, 256, 0, stream>>>(x, W1, b1, W2, b2, Wout, bout, out);
    }
}